// Round 9
// baseline (96.255 us; speedup 1.0000x reference)
//
#include <hip/hip_runtime.h>

#define NG 256
#define NPG 64
#define DM 64
#define DFF 256
#define NL 2
#define DEG 8
#define NCLS 10
#define S68 68
#define S132 132

// LDS pool offsets (u32 words)
#define HB0 0              // [64][68] packed-split h
#define AB0 4352           // [64][68] T (fp32) -> struct/attn (packed)
#define BB0 8704           // [64][68] agg/k/o (fp32)
#define QB0 13056          // [64][68] U/q (fp32)
#define F10 17408          // [64][68] v (fp32) then [64][132] packed f1 half
#define POOLW 25856        // 103.4 KB

// prepped weight buffer: u16 elements, separate hi/lo bf16 planes
// W64: matrix m (0..11): hi at m*8192 + c*64 + k, lo at +4096
#define FF1B 98304         // per layer +lay*32768: hi c*64+k (c<256), lo +16384
#define FF2B 163840        // per layer +lay*32768: hi c*256+k (c<64), lo +16384
#define WTOT 229376        // u16 count; 458 KB

__device__ __align__(16) unsigned short g_w[WTOT];   // fallback if d_ws too small

typedef __attribute__((ext_vector_type(4))) float f32x4;
typedef __attribute__((ext_vector_type(4))) unsigned int u32x4;
typedef __attribute__((ext_vector_type(8))) __bf16 bf16x8;

// ---- split-bf16 packing: u32 = (lo16 << 16) | hi16,  x ~= hi + lo ----
__device__ __forceinline__ unsigned int packsplit(float x) {
    union { float f; unsigned int u; } a; a.f = x;
    const unsigned int t = a.u;
    const unsigned int hi = (t + 0x7FFFu + ((t >> 16) & 1u)) >> 16;   // RNE bf16(x)
    union { unsigned int u; float f; } hf; hf.u = hi << 16;
    union { float f; unsigned int u; } b; b.f = x - hf.f;
    const unsigned int tl = b.u;
    const unsigned int lo = (tl + 0x7FFFu + ((tl >> 16) & 1u)) & 0xFFFF0000u;
    return hi | lo;
}
__device__ __forceinline__ float unpackf(unsigned int u) {
    union { unsigned int u; float f; } h, l;
    h.u = u << 16;
    l.u = u & 0xFFFF0000u;
    return h.f + l.f;
}

// extract hi/lo bf16x8 frags from 8 packed u32 (A-side only)
__device__ __forceinline__ void extract(u32x4 p0, u32x4 p1, u32x4& hi, u32x4& lo) {
    hi[0] = (p0[0] & 0xFFFFu) | (p0[1] << 16);
    hi[1] = (p0[2] & 0xFFFFu) | (p0[3] << 16);
    hi[2] = (p1[0] & 0xFFFFu) | (p1[1] << 16);
    hi[3] = (p1[2] & 0xFFFFu) | (p1[3] << 16);
    lo[0] = (p0[0] >> 16) | (p0[1] & 0xFFFF0000u);
    lo[1] = (p0[2] >> 16) | (p0[3] & 0xFFFF0000u);
    lo[2] = (p1[0] >> 16) | (p1[1] & 0xFFFF0000u);
    lo[3] = (p1[2] >> 16) | (p1[3] & 0xFFFF0000u);
}

__device__ __forceinline__ bf16x8 ld8(const unsigned short* p) { return *(const bf16x8*)p; }

__device__ __forceinline__ f32x4 mfma16(u32x4 a, bf16x8 b, f32x4 c) {
    return __builtin_amdgcn_mfma_f32_16x16x32_bf16(__builtin_bit_cast(bf16x8, a), b, c, 0, 0, 0);
}

// one K=32 A-chunk, pre-extracted
struct AP2 { u32x4 h, l; };
__device__ __forceinline__ AP2 loadA32(const unsigned int* p) {
    const u32x4 a0 = *(const u32x4*)p, a1 = *(const u32x4*)(p + 4);
    AP2 r; extract(a0, a1, r.h, r.l); return r;
}

// acc += A_chunk * B_chunk (B from hi/lo planes, no extract), 3 MFMAs
__device__ __forceinline__ f32x4 chunkp(const AP2& a, const unsigned short* bhp, int plane,
                                        f32x4 acc) {
    const bf16x8 bh = ld8(bhp), bl = ld8(bhp + plane);
    acc = mfma16(a.h, bh, acc);
    acc = mfma16(a.h, bl, acc);
    acc = mfma16(a.l, bh, acc);
    return acc;
}

// full 64-K matmul tile given pre-extracted A chunks
__device__ __forceinline__ f32x4 mm64p(const AP2& a0, const AP2& a1,
                                       const unsigned short* Wh, int boff) {
    f32x4 acc = {0.f, 0.f, 0.f, 0.f};
    acc = chunkp(a0, Wh + boff,      4096, acc);
    acc = chunkp(a1, Wh + boff + 32, 4096, acc);
    return acc;
}

__device__ __forceinline__ void dwrite_f32(float* dst, f32x4 acc, int wr, int wc, int l) {
    const int col = (wc << 4) + (l & 15);
    const int r0 = (wr << 4) + ((l >> 4) << 2);
#pragma unroll
    for (int r = 0; r < 4; ++r) dst[(r0 + r) * S68 + col] = acc[r];
}

__device__ __forceinline__ void layernorm(const float* src, unsigned int* dst,
                                          const float* gp, const float* bp, int n, int jg) {
    const f32x4 v = *(const f32x4*)(src + n * S68 + jg);
    float s1 = v[0] + v[1] + v[2] + v[3];
    float s2 = v[0]*v[0] + v[1]*v[1] + v[2]*v[2] + v[3]*v[3];
    s1 += __shfl_xor(s1, 1); s1 += __shfl_xor(s1, 2);
    s1 += __shfl_xor(s1, 4); s1 += __shfl_xor(s1, 8);
    s2 += __shfl_xor(s2, 1); s2 += __shfl_xor(s2, 2);
    s2 += __shfl_xor(s2, 4); s2 += __shfl_xor(s2, 8);
    const float mean = s1 * 0.015625f;
    const float var  = s2 * 0.015625f - mean * mean;
    const float rstd = rsqrtf(var + 1e-5f);
    const f32x4 gm = *(const f32x4*)(gp + jg);
    const f32x4 bt = *(const f32x4*)(bp + jg);
    u32x4 p;
#pragma unroll
    for (int j = 0; j < 4; ++j) p[j] = packsplit((v[j] - mean) * rstd * gm[j] + bt[j]);
    *(u32x4*)(dst + n * S68 + jg) = p;
}

// ---- weight prep: fp32 -> transposed hi/lo bf16 planes ----
extern "C" __global__ void gt_prep(const float* __restrict__ Wgn, const float* __restrict__ Wgs,
                                   const float* __restrict__ Wk, const float* __restrict__ Wq,
                                   const float* __restrict__ Wv, const float* __restrict__ Wo,
                                   const float* __restrict__ fW1, const float* __restrict__ fW2,
                                   unsigned short* wout)
{
    unsigned short* W = wout ? wout : g_w;
    const int t = blockIdx.x * 256 + threadIdx.x;   // 0..114687
    float v; int dhi, plane;
    if (t < 49152) {
        const int m = t >> 12, r = t & 4095, k = r >> 6, c = r & 63;
        const int lay = m / 6, idx = m - lay * 6;
        const float* s;
        switch (idx) { case 0: s = Wgn; break; case 1: s = Wgs; break;
                       case 2: s = Wk;  break; case 3: s = Wq;  break;
                       case 4: s = Wv;  break; default: s = Wo; }
        v = s[lay * 4096 + k * 64 + c];
        dhi = (m << 13) + (c << 6) + k;
        plane = 4096;
    } else if (t < 81920) {
        const int r = t - 49152, lay = r >> 14, q = r & 16383, k = q >> 8, c = q & 255;
        v = fW1[lay * 16384 + k * 256 + c];
        dhi = FF1B + lay * 32768 + (c << 6) + k;
        plane = 16384;
    } else {
        const int r = t - 81920, lay = r >> 14, q = r & 16383, k = q >> 6, c = q & 63;
        v = fW2[lay * 16384 + k * 64 + c];
        dhi = FF2B + lay * 32768 + (c << 8) + k;
        plane = 16384;
    }
    union { float f; unsigned int u; } a; a.f = v;
    const unsigned int hi = (a.u + 0x7FFFu + ((a.u >> 16) & 1u)) >> 16;
    union { unsigned int u; float f; } hf; hf.u = hi << 16;
    union { float f; unsigned int u; } b; b.f = v - hf.f;
    const unsigned int lo = (b.u + 0x7FFFu + ((b.u >> 16) & 1u)) >> 16;
    W[dhi] = (unsigned short)hi;
    W[dhi + plane] = (unsigned short)lo;
}

extern "C" __global__ __launch_bounds__(1024)
void gt_main(const int* __restrict__ x, const int* __restrict__ e_src,
             const float* __restrict__ emb, const float* __restrict__ bo,
             const float* __restrict__ l1g, const float* __restrict__ l1b,
             const float* __restrict__ fb1, const float* __restrict__ fb2,
             const float* __restrict__ l2g, const float* __restrict__ l2b,
             const float* __restrict__ cW1, const float* __restrict__ cb1,
             const float* __restrict__ cW2, const float* __restrict__ cb2,
             const unsigned short* __restrict__ wext,
             float* __restrict__ out)
{
    const unsigned short* gww = wext ? wext : g_w;

    __shared__ __align__(16) unsigned int pool[POOLW];
    unsigned int* Hb  = pool + HB0;
    unsigned int* Abu = pool + AB0;  float* Abf = (float*)Abu;
    float* Bbf = (float*)(pool + BB0);
    float* Qbf = (float*)(pool + QB0);
    float* Vbf = (float*)(pool + F10);
    unsigned int* F1  = pool + F10;

    const int g = blockIdx.x, tid = threadIdx.x;
    const int w = tid >> 6, l = tid & 63;
    const int wr = w >> 2, wc = w & 3;
    const int n = tid >> 4, jg = (tid & 15) << 2;

    const int arow = (wr << 4) + (l & 15);
    const int bcol = (wc << 4) + (l & 15);
    const int kg   = (l >> 4) << 3;
    const int boff = (bcol << 6) + kg;

    // ---- h = emb[x] (packed) ----
    {
        const int lbl = x[g * NPG + n];
        const f32x4 e = *(const f32x4*)(emb + lbl * DM + jg);
        u32x4 p;
#pragma unroll
        for (int j = 0; j < 4; ++j) p[j] = packsplit(e[j]);
        *(u32x4*)(Hb + n * S68 + jg) = p;
    }
    __syncthreads();

    for (int lay = 0; lay < NL; ++lay) {
        const unsigned short* Wm = gww + ((lay * 6) << 13);

        // p1: T = h@Wgn -> Abf ; U = h@Wgs -> Qbf ; v = h@Wv -> Vbf (shared A-frags)
        {
            const unsigned int* Ar = Hb + arow * S68;
            const AP2 a0 = loadA32(Ar + kg), a1 = loadA32(Ar + kg + 32);
            dwrite_f32(Abf, mm64p(a0, a1, Wm,               boff), wr, wc, l);
            dwrite_f32(Qbf, mm64p(a0, a1, Wm + (1 << 13),   boff), wr, wc, l);
            dwrite_f32(Vbf, mm64p(a0, a1, Wm + (4 << 13),   boff), wr, wc, l);
        }
        __syncthreads();

        // p2: agg over 8 incoming edges of T -> Bbf
        {
            f32x4 s = {0.f, 0.f, 0.f, 0.f};
            const int* es = e_src + (g * NPG + n) * DEG;
#pragma unroll
            for (int k = 0; k < DEG; ++k) {
                const int sr = es[k] - g * NPG;
                const f32x4 v4 = *(const f32x4*)(Abf + sr * S68 + jg);
                s[0] += v4[0]; s[1] += v4[1]; s[2] += v4[2]; s[3] += v4[3];
            }
            *(f32x4*)(Bbf + n * S68 + jg) = s;
        }
        __syncthreads();

        // p3: struct = h + relu(U + agg) -> Abu (packed, elementwise)
        {
            const f32x4 u4 = *(const f32x4*)(Qbf + n * S68 + jg);
            const f32x4 a4 = *(const f32x4*)(Bbf + n * S68 + jg);
            const u32x4 hp = *(const u32x4*)(Hb + n * S68 + jg);
            u32x4 p;
#pragma unroll
            for (int j = 0; j < 4; ++j)
                p[j] = packsplit(unpackf(hp[j]) + fmaxf(u4[j] + a4[j], 0.f));
            *(u32x4*)(Abu + n * S68 + jg) = p;
        }
        __syncthreads();

        // p4: k = St@Wk -> Bbf ; q = St@Wq -> Qbf (shared A-frags)
        {
            const unsigned int* Ar = Abu + arow * S68;
            const AP2 a0 = loadA32(Ar + kg), a1 = loadA32(Ar + kg + 32);
            dwrite_f32(Bbf, mm64p(a0, a1, Wm + (2 << 13), boff), wr, wc, l);
            dwrite_f32(Qbf, mm64p(a0, a1, Wm + (3 << 13), boff), wr, wc, l);
        }
        __syncthreads();

        // p5: attention (online softmax); k in Bbf, v in Vbf, q in Qbf -> attn packed -> Abu
        {
            const f32x4 qr = *(const f32x4*)(Qbf + n * S68 + jg);
            const float q0 = qr[0] * 0.25f, q1 = qr[1] * 0.25f;
            const float q2 = qr[2] * 0.25f, q3 = qr[3] * 0.25f;
            float o0 = 0.f, o1 = 0.f, o2 = 0.f, o3 = 0.f, m = -1e30f, ls = 0.f;
#pragma unroll 4
            for (int sr = 0; sr < NPG; ++sr) {
                const f32x4 k4 = *(const f32x4*)(Bbf + sr * S68 + jg);
                float s = q0*k4[0] + q1*k4[1] + q2*k4[2] + q3*k4[3];
                s += __shfl_xor(s, 1);
                s += __shfl_xor(s, 2);
                const float mn  = fmaxf(m, s);
                const float fac = __expf(m - mn), wg = __expf(s - mn);
                ls = ls * fac + wg;
                const f32x4 v4 = *(const f32x4*)(Vbf + sr * S68 + jg);
                o0 = o0 * fac + wg * v4[0]; o1 = o1 * fac + wg * v4[1];
                o2 = o2 * fac + wg * v4[2]; o3 = o3 * fac + wg * v4[3];
                m = mn;
            }
            const float il = 1.f / ls;
            u32x4 p;
            p[0] = packsplit(o0 * il); p[1] = packsplit(o1 * il);
            p[2] = packsplit(o2 * il); p[3] = packsplit(o3 * il);
            *(u32x4*)(Abu + n * S68 + jg) = p;
        }
        __syncthreads();

        // p6: o = attn@Wo + bo + h -> Bbf (pre-LN1)
        {
            const unsigned int* Ar = Abu + arow * S68;
            const AP2 a0 = loadA32(Ar + kg), a1 = loadA32(Ar + kg + 32);
            const f32x4 acc = mm64p(a0, a1, Wm + (5 << 13), boff);
            const int r0 = (wr << 4) + ((l >> 4) << 2);
            const float bb = bo[lay * DM + bcol];
#pragma unroll
            for (int r = 0; r < 4; ++r) {
                const int row = r0 + r;
                Bbf[row * S68 + bcol] = acc[r] + bb + unpackf(Hb[row * S68 + bcol]);
            }
        }
        __syncthreads();

        layernorm(Bbf, Hb, l1g + lay * DM, l1b + lay * DM, n, jg);
        __syncthreads();

        // ---- FF in 2 halves of 128 hidden ----
        f32x4 f2 = {0.f, 0.f, 0.f, 0.f};
        for (int hf = 0; hf < 2; ++hf) {
            // FF1: 2 col-tiles per wave -> F1 packed [64][132]
            {
                const unsigned int* Ar = Hb + arow * S68;
                const AP2 a0 = loadA32(Ar + kg), a1 = loadA32(Ar + kg + 32);
                const unsigned short* B1 = gww + FF1B + lay * 32768;
                const int r0 = (wr << 4) + ((l >> 4) << 2);
#pragma unroll
                for (int t = 0; t < 2; ++t) {
                    const int tc = ((wc + 4 * t) << 4) + (l & 15);   // col within half
                    const int cg = hf * 128 + tc;
                    f32x4 acc = {0.f, 0.f, 0.f, 0.f};
                    acc = chunkp(a0, B1 + (cg << 6) + kg,      16384, acc);
                    acc = chunkp(a1, B1 + (cg << 6) + kg + 32, 16384, acc);
                    const float b1 = fb1[lay * DFF + cg];
#pragma unroll
                    for (int r = 0; r < 4; ++r)
                        F1[(r0 + r) * S132 + tc] = packsplit(fmaxf(acc[r] + b1, 0.f));
                }
            }
            __syncthreads();
            // FF2: K=128 of this half, accumulate into f2
            {
                const unsigned int* Ar = F1 + arow * S132;
                const unsigned short* B2 = gww + FF2B + lay * 32768 + (bcol << 8) + hf * 128;
#pragma unroll
                for (int ch = 0; ch < 4; ++ch) {
                    const AP2 ac = loadA32(Ar + kg + 32 * ch);
                    f2 = chunkp(ac, B2 + kg + 32 * ch, 16384, f2);
                }
            }
            __syncthreads();   // before next half overwrites F1
        }
        // FF2 epilogue: + b2 + h -> Abf (pre-LN2)
        {
            const int r0 = (wr << 4) + ((l >> 4) << 2);
            const float bb = fb2[lay * DM + bcol];
#pragma unroll
            for (int r = 0; r < 4; ++r) {
                const int row = r0 + r;
                Abf[row * S68 + bcol] = f2[r] + bb + unpackf(Hb[row * S68 + bcol]);
            }
        }
        __syncthreads();

        layernorm(Abf, Hb, l2g + lay * DM, l2b + lay * DM, n, jg);
        __syncthreads();
    }

    // ---- mean pool + classifier ----
    if (tid < DM) {
        float s = 0.f;
        for (int nn = 0; nn < NPG; ++nn) s += unpackf(Hb[nn * S68 + tid]);
        Abf[tid] = s * 0.015625f;
    }
    __syncthreads();
    if (tid < DM) {
        float acc = cb1[tid];
        for (int i = 0; i < DM; ++i) acc = fmaf(Abf[i], cW1[i * DM + tid], acc);
        Bbf[tid] = fmaxf(acc, 0.f);
    }
    __syncthreads();
    if (tid < NCLS) {
        float acc = cb2[tid];
        for (int i = 0; i < DM; ++i) acc = fmaf(Bbf[i], cW2[i * NCLS + tid], acc);
        out[g * NCLS + tid] = acc;
    }
}

extern "C" void kernel_launch(void* const* d_in, const int* in_sizes, int n_in,
                              void* d_out, int out_size, void* d_ws, size_t ws_size,
                              hipStream_t stream) {
    // dict order: x0 e1 c2 b3 emb4 Wgs5 Wgn6 Wq7 Wk8 Wv9 Wo10 bo11 l1g12 l1b13
    //             fW1_14 fb1_15 fW2_16 fb2_17 l2g18 l2b19 cW1_20 cb1_21 cW2_22 cb2_23
    unsigned short* wbuf =
        (d_ws != nullptr && ws_size >= (size_t)WTOT * 2) ? (unsigned short*)d_ws : nullptr;
    gt_prep<<<dim3(448), dim3(256), 0, stream>>>(
        (const float*)d_in[6], (const float*)d_in[5],   // Wgn, Wgs
        (const float*)d_in[8], (const float*)d_in[7],   // Wk, Wq
        (const float*)d_in[9], (const float*)d_in[10],  // Wv, Wo
        (const float*)d_in[14], (const float*)d_in[16],
        wbuf);
    gt_main<<<dim3(NG), dim3(1024), 0, stream>>>(
        (const int*)d_in[0], (const int*)d_in[1],
        (const float*)d_in[4], (const float*)d_in[11],
        (const float*)d_in[12], (const float*)d_in[13],
        (const float*)d_in[15], (const float*)d_in[17],
        (const float*)d_in[18], (const float*)d_in[19],
        (const float*)d_in[20], (const float*)d_in[21],
        (const float*)d_in[22], (const float*)d_in[23],
        wbuf,
        (float*)d_out);
}

// Round 10
// 82.540 us; speedup vs baseline: 1.1662x; 1.1662x over previous
//
#include <hip/hip_runtime.h>

#define NG 256
#define NPG 64
#define DM 64
#define DFF 256
#define NL 2
#define DEG 8
#define NCLS 10
#define S68 68
#define S132 132

// LDS pool offsets (u32 words)
#define HB0 0              // [64][68] packed-split h
#define AB0 4352           // [64][68] T (fp32) -> struct/attn (packed)
#define BB0 8704           // [64][68] agg/k/o (fp32)
#define QB0 13056          // [64][68] U/q (fp32)
#define F10 17408          // [64][68] v (fp32) then [64][132] packed f1 half
#define WSB 25856          // 3 x 4096-word staged weight pair buffers (48 KB)
#define POOLW 38144        // 152.6 KB

// prepped weight buffer (packed-split u32 words)
// W64 m=0..11 at m*4096: word (c<<6) | (((k>>2)^(c&7))<<2) | (k&3)   [swizzled]
#define FF1B 49152         // + lay*16384 + (c<<6) + k   (c<256, k<64)
#define FF2B 81920         // + lay*16384 + (c<<8) + k   (c<64, k<256)
#define WTOT 114688        // u32 words; 458 KB

__device__ __align__(16) unsigned int g_w[WTOT];   // fallback if d_ws too small

typedef __attribute__((ext_vector_type(4))) float f32x4;
typedef __attribute__((ext_vector_type(4))) unsigned int u32x4;
typedef __attribute__((ext_vector_type(8))) __bf16 bf16x8;

// ---- split-bf16 packing: u32 = (lo16 << 16) | hi16,  x ~= hi + lo ----
__device__ __forceinline__ unsigned int packsplit(float x) {
    union { float f; unsigned int u; } a; a.f = x;
    const unsigned int t = a.u;
    const unsigned int hi = (t + 0x7FFFu + ((t >> 16) & 1u)) >> 16;   // RNE bf16(x)
    union { unsigned int u; float f; } hf; hf.u = hi << 16;
    union { float f; unsigned int u; } b; b.f = x - hf.f;
    const unsigned int tl = b.u;
    const unsigned int lo = (tl + 0x7FFFu + ((tl >> 16) & 1u)) & 0xFFFF0000u;
    return hi | lo;
}
__device__ __forceinline__ float unpackf(unsigned int u) {
    union { unsigned int u; float f; } h, l;
    h.u = u << 16;
    l.u = u & 0xFFFF0000u;
    return h.f + l.f;
}

// extract hi/lo bf16x8 frags from 8 packed u32
__device__ __forceinline__ void extract(u32x4 p0, u32x4 p1, u32x4& hi, u32x4& lo) {
    hi[0] = (p0[0] & 0xFFFFu) | (p0[1] << 16);
    hi[1] = (p0[2] & 0xFFFFu) | (p0[3] << 16);
    hi[2] = (p1[0] & 0xFFFFu) | (p1[1] << 16);
    hi[3] = (p1[2] & 0xFFFFu) | (p1[3] << 16);
    lo[0] = (p0[0] >> 16) | (p0[1] & 0xFFFF0000u);
    lo[1] = (p0[2] >> 16) | (p0[3] & 0xFFFF0000u);
    lo[2] = (p1[0] >> 16) | (p1[1] & 0xFFFF0000u);
    lo[3] = (p1[2] >> 16) | (p1[3] & 0xFFFF0000u);
}

__device__ __forceinline__ f32x4 mfma16(u32x4 a, u32x4 b, f32x4 c) {
    return __builtin_amdgcn_mfma_f32_16x16x32_bf16(
        __builtin_bit_cast(bf16x8, a), __builtin_bit_cast(bf16x8, b), c, 0, 0, 0);
}

// pre-extracted A chunk (K=32)
struct AP2 { u32x4 h, l; };
__device__ __forceinline__ AP2 loadA32(const unsigned int* p) {
    const u32x4 a0 = *(const u32x4*)p, a1 = *(const u32x4*)(p + 4);
    AP2 r; extract(a0, a1, r.h, r.l); return r;
}

// acc += A_chunk * B_chunk given B's 8 packed words (3 MFMAs: hh, hl, lh)
__device__ __forceinline__ f32x4 chunkAB(const AP2& a, u32x4 w0, u32x4 w1, f32x4 acc) {
    u32x4 bh, bl;
    extract(w0, w1, bh, bl);
    acc = mfma16(a.h, bh, acc);
    acc = mfma16(a.h, bl, acc);
    acc = mfma16(a.l, bh, acc);
    return acc;
}
// B from global packed [c][k] (FF path)
__device__ __forceinline__ f32x4 chunkG(const AP2& a, const unsigned int* p, f32x4 acc) {
    return chunkAB(a, *(const u32x4*)p, *(const u32x4*)(p + 4), acc);
}

// full K=64 tile, B from swizzled staged LDS pair
__device__ __forceinline__ f32x4 mmS(const AP2& a0, const AP2& a1,
                                     const unsigned int* Wb, int bcol, int kg) {
    const int rb = bcol << 6, cx = bcol & 7, q0 = kg >> 2;   // q0 in {0,2,4,6}
    const u32x4 w00 = *(const u32x4*)(Wb + rb + (((q0    ) ^ cx) << 2));
    const u32x4 w01 = *(const u32x4*)(Wb + rb + (((q0 + 1) ^ cx) << 2));
    const u32x4 w10 = *(const u32x4*)(Wb + rb + (((q0 + 8) ^ cx) << 2));
    const u32x4 w11 = *(const u32x4*)(Wb + rb + (((q0 + 9) ^ cx) << 2));
    f32x4 acc = {0.f, 0.f, 0.f, 0.f};
    acc = chunkAB(a0, w00, w01, acc);
    acc = chunkAB(a1, w10, w11, acc);
    return acc;
}

__device__ __forceinline__ void dwrite_f32(float* dst, f32x4 acc, int wr, int wc, int l) {
    const int col = (wc << 4) + (l & 15);
    const int r0 = (wr << 4) + ((l >> 4) << 2);
#pragma unroll
    for (int r = 0; r < 4; ++r) dst[(r0 + r) * S68 + col] = acc[r];
}

__device__ __forceinline__ void layernorm(const float* src, unsigned int* dst,
                                          const float* gp, const float* bp, int n, int jg) {
    const f32x4 v = *(const f32x4*)(src + n * S68 + jg);
    float s1 = v[0] + v[1] + v[2] + v[3];
    float s2 = v[0]*v[0] + v[1]*v[1] + v[2]*v[2] + v[3]*v[3];
    s1 += __shfl_xor(s1, 1); s1 += __shfl_xor(s1, 2);
    s1 += __shfl_xor(s1, 4); s1 += __shfl_xor(s1, 8);
    s2 += __shfl_xor(s2, 1); s2 += __shfl_xor(s2, 2);
    s2 += __shfl_xor(s2, 4); s2 += __shfl_xor(s2, 8);
    const float mean = s1 * 0.015625f;
    const float var  = s2 * 0.015625f - mean * mean;
    const float rstd = rsqrtf(var + 1e-5f);
    const f32x4 gm = *(const f32x4*)(gp + jg);
    const f32x4 bt = *(const f32x4*)(bp + jg);
    u32x4 p;
#pragma unroll
    for (int j = 0; j < 4; ++j) p[j] = packsplit((v[j] - mean) * rstd * gm[j] + bt[j]);
    *(u32x4*)(dst + n * S68 + jg) = p;
}

// ---- weight prep: fp32 -> transposed packed-split u32 (W64 bank-swizzled) ----
extern "C" __global__ void gt_prep(const float* __restrict__ Wgn, const float* __restrict__ Wgs,
                                   const float* __restrict__ Wk, const float* __restrict__ Wq,
                                   const float* __restrict__ Wv, const float* __restrict__ Wo,
                                   const float* __restrict__ fW1, const float* __restrict__ fW2,
                                   unsigned int* wout)
{
    unsigned int* W = wout ? wout : g_w;
    const int t = blockIdx.x * 256 + threadIdx.x;   // 0..114687 == WTOT
    float v; int d;
    if (t < 49152) {
        const int m = t >> 12, r = t & 4095, k = r >> 6, c = r & 63;
        const int lay = m / 6, idx = m - lay * 6;
        const float* s;
        switch (idx) { case 0: s = Wgn; break; case 1: s = Wgs; break;
                       case 2: s = Wk;  break; case 3: s = Wq;  break;
                       case 4: s = Wv;  break; default: s = Wo; }
        v = s[lay * 4096 + k * 64 + c];
        d = (m << 12) + (c << 6) + ((((k >> 2) ^ (c & 7)) << 2) | (k & 3));  // swizzled
    } else if (t < 81920) {
        const int r = t - 49152, lay = r >> 14, q = r & 16383, k = q >> 8, c = q & 255;
        v = fW1[lay * 16384 + k * 256 + c];
        d = FF1B + lay * 16384 + (c << 6) + k;
    } else {
        const int r = t - 81920, lay = r >> 14, q = r & 16383, k = q >> 6, c = q & 63;
        v = fW2[lay * 16384 + k * 64 + c];
        d = FF2B + lay * 16384 + (c << 8) + k;
    }
    W[d] = packsplit(v);
}

extern "C" __global__ __launch_bounds__(1024)
void gt_main(const int* __restrict__ x, const int* __restrict__ e_src,
             const float* __restrict__ emb, const float* __restrict__ bo,
             const float* __restrict__ l1g, const float* __restrict__ l1b,
             const float* __restrict__ fb1, const float* __restrict__ fb2,
             const float* __restrict__ l2g, const float* __restrict__ l2b,
             const float* __restrict__ cW1, const float* __restrict__ cb1,
             const float* __restrict__ cW2, const float* __restrict__ cb2,
             const unsigned int* __restrict__ wext,
             float* __restrict__ out)
{
    const unsigned int* gw = wext ? wext : g_w;

    __shared__ __align__(16) unsigned int pool[POOLW];
    unsigned int* Hb  = pool + HB0;
    unsigned int* Abu = pool + AB0;  float* Abf = (float*)Abu;
    float* Bbf = (float*)(pool + BB0);
    float* Qbf = (float*)(pool + QB0);
    float* Vbf = (float*)(pool + F10);
    unsigned int* F1  = pool + F10;
    unsigned int* Wb0 = pool + WSB;
    unsigned int* Wb1 = pool + WSB + 4096;
    unsigned int* Wb2 = pool + WSB + 8192;

    const int g = blockIdx.x, tid = threadIdx.x;
    const int w = tid >> 6, l = tid & 63;
    const int wr = w >> 2, wc = w & 3;
    const int n = tid >> 4, jg = (tid & 15) << 2;

    const int arow = (wr << 4) + (l & 15);
    const int bcol = (wc << 4) + (l & 15);
    const int kg   = (l >> 4) << 3;
    const int t4   = tid << 2;

    // ---- h = emb[x] (packed) ; prologue staging of Wgn0/Wgs0/Wv0 ----
    {
        const u32x4 s0 = *(const u32x4*)(gw + (0 << 12) + t4);
        const u32x4 s1 = *(const u32x4*)(gw + (1 << 12) + t4);
        const u32x4 s2 = *(const u32x4*)(gw + (4 << 12) + t4);
        const int lbl = x[g * NPG + n];
        const f32x4 e = *(const f32x4*)(emb + lbl * DM + jg);
        u32x4 p;
#pragma unroll
        for (int j = 0; j < 4; ++j) p[j] = packsplit(e[j]);
        *(u32x4*)(Hb + n * S68 + jg) = p;
        *(u32x4*)(Wb0 + t4) = s0;
        *(u32x4*)(Wb1 + t4) = s1;
        *(u32x4*)(Wb2 + t4) = s2;
    }
    __syncthreads();

    for (int lay = 0; lay < NL; ++lay) {
        const bool pre = (lay + 1 < NL);

        // p1: T = h@Wgn -> Abf ; U = h@Wgs -> Qbf ; v = h@Wv -> Vbf (B from staged LDS)
        {
            const unsigned int* Ar = Hb + arow * S68;
            const AP2 a0 = loadA32(Ar + kg), a1 = loadA32(Ar + kg + 32);
            dwrite_f32(Abf, mmS(a0, a1, Wb0, bcol, kg), wr, wc, l);
            dwrite_f32(Qbf, mmS(a0, a1, Wb1, bcol, kg), wr, wc, l);
            dwrite_f32(Vbf, mmS(a0, a1, Wb2, bcol, kg), wr, wc, l);
        }
        __syncthreads();

        // p2: agg over 8 incoming edges of T -> Bbf ; stage Wk->b0, Wq->b1
        {
            const u32x4 t0 = *(const u32x4*)(gw + ((lay * 6 + 2) << 12) + t4);
            const u32x4 t1 = *(const u32x4*)(gw + ((lay * 6 + 3) << 12) + t4);
            f32x4 s = {0.f, 0.f, 0.f, 0.f};
            const int* es = e_src + (g * NPG + n) * DEG;
#pragma unroll
            for (int k = 0; k < DEG; ++k) {
                const int sr = es[k] - g * NPG;
                const f32x4 v4 = *(const f32x4*)(Abf + sr * S68 + jg);
                s[0] += v4[0]; s[1] += v4[1]; s[2] += v4[2]; s[3] += v4[3];
            }
            *(f32x4*)(Bbf + n * S68 + jg) = s;
            *(u32x4*)(Wb0 + t4) = t0;
            *(u32x4*)(Wb1 + t4) = t1;
        }
        __syncthreads();

        // p3: struct = h + relu(U + agg) -> Abu (packed) ; stage Wo->b2
        {
            const u32x4 t2 = *(const u32x4*)(gw + ((lay * 6 + 5) << 12) + t4);
            const f32x4 u4 = *(const f32x4*)(Qbf + n * S68 + jg);
            const f32x4 a4 = *(const f32x4*)(Bbf + n * S68 + jg);
            const u32x4 hp = *(const u32x4*)(Hb + n * S68 + jg);
            u32x4 p;
#pragma unroll
            for (int j = 0; j < 4; ++j)
                p[j] = packsplit(unpackf(hp[j]) + fmaxf(u4[j] + a4[j], 0.f));
            *(u32x4*)(Abu + n * S68 + jg) = p;
            *(u32x4*)(Wb2 + t4) = t2;
        }
        __syncthreads();

        // p4: k = St@Wk -> Bbf ; q = St@Wq -> Qbf (staged B)
        {
            const unsigned int* Ar = Abu + arow * S68;
            const AP2 a0 = loadA32(Ar + kg), a1 = loadA32(Ar + kg + 32);
            dwrite_f32(Bbf, mmS(a0, a1, Wb0, bcol, kg), wr, wc, l);
            dwrite_f32(Qbf, mmS(a0, a1, Wb1, bcol, kg), wr, wc, l);
        }
        __syncthreads();

        // p5: attention (online softmax) -> Abu ; stage next-layer Wgn->b0, Wgs->b1
        {
            u32x4 t0, t1;
            if (pre) {
                t0 = *(const u32x4*)(gw + (((lay + 1) * 6 + 0) << 12) + t4);
                t1 = *(const u32x4*)(gw + (((lay + 1) * 6 + 1) << 12) + t4);
            }
            const f32x4 qr = *(const f32x4*)(Qbf + n * S68 + jg);
            const float q0 = qr[0] * 0.25f, q1 = qr[1] * 0.25f;
            const float q2 = qr[2] * 0.25f, q3 = qr[3] * 0.25f;
            float o0 = 0.f, o1 = 0.f, o2 = 0.f, o3 = 0.f, m = -1e30f, ls = 0.f;
#pragma unroll 4
            for (int sr = 0; sr < NPG; ++sr) {
                const f32x4 k4 = *(const f32x4*)(Bbf + sr * S68 + jg);
                float s = q0*k4[0] + q1*k4[1] + q2*k4[2] + q3*k4[3];
                s += __shfl_xor(s, 1);
                s += __shfl_xor(s, 2);
                const float mn  = fmaxf(m, s);
                const float fac = __expf(m - mn), wg = __expf(s - mn);
                ls = ls * fac + wg;
                const f32x4 v4 = *(const f32x4*)(Vbf + sr * S68 + jg);
                o0 = o0 * fac + wg * v4[0]; o1 = o1 * fac + wg * v4[1];
                o2 = o2 * fac + wg * v4[2]; o3 = o3 * fac + wg * v4[3];
                m = mn;
            }
            const float il = 1.f / ls;
            u32x4 p;
            p[0] = packsplit(o0 * il); p[1] = packsplit(o1 * il);
            p[2] = packsplit(o2 * il); p[3] = packsplit(o3 * il);
            *(u32x4*)(Abu + n * S68 + jg) = p;
            if (pre) {
                *(u32x4*)(Wb0 + t4) = t0;
                *(u32x4*)(Wb1 + t4) = t1;
            }
        }
        __syncthreads();

        // p6: o = attn@Wo + bo + h -> Bbf (pre-LN1), staged B in b2
        {
            const unsigned int* Ar = Abu + arow * S68;
            const AP2 a0 = loadA32(Ar + kg), a1 = loadA32(Ar + kg + 32);
            const f32x4 acc = mmS(a0, a1, Wb2, bcol, kg);
            const int r0 = (wr << 4) + ((l >> 4) << 2);
            const float bb = bo[lay * DM + bcol];
#pragma unroll
            for (int r = 0; r < 4; ++r) {
                const int row = r0 + r;
                Bbf[row * S68 + bcol] = acc[r] + bb + unpackf(Hb[row * S68 + bcol]);
            }
        }
        __syncthreads();

        // LN1 ; stage next-layer Wv->b2
        {
            u32x4 t2;
            if (pre) t2 = *(const u32x4*)(gw + (((lay + 1) * 6 + 4) << 12) + t4);
            layernorm(Bbf, Hb, l1g + lay * DM, l1b + lay * DM, n, jg);
            if (pre) *(u32x4*)(Wb2 + t4) = t2;
        }
        __syncthreads();

        // ---- FF in 2 halves of 128 hidden (B from global, packed) ----
        f32x4 f2 = {0.f, 0.f, 0.f, 0.f};
        for (int hf = 0; hf < 2; ++hf) {
            // FF1: 2 col-tiles per wave -> F1 packed [64][132]
            {
                const unsigned int* Ar = Hb + arow * S68;
                const AP2 a0 = loadA32(Ar + kg), a1 = loadA32(Ar + kg + 32);
                const unsigned int* B1 = gw + FF1B + lay * 16384;
                const int r0 = (wr << 4) + ((l >> 4) << 2);
#pragma unroll
                for (int t = 0; t < 2; ++t) {
                    const int tc = ((wc + 4 * t) << 4) + (l & 15);   // col within half
                    const int cg = hf * 128 + tc;
                    const unsigned int* Bp = B1 + (cg << 6);
                    f32x4 acc = {0.f, 0.f, 0.f, 0.f};
                    acc = chunkG(a0, Bp + kg,      acc);
                    acc = chunkG(a1, Bp + kg + 32, acc);
                    const float b1 = fb1[lay * DFF + cg];
#pragma unroll
                    for (int r = 0; r < 4; ++r)
                        F1[(r0 + r) * S132 + tc] = packsplit(fmaxf(acc[r] + b1, 0.f));
                }
            }
            __syncthreads();
            // FF2: K=128 of this half, accumulate into f2
            {
                const unsigned int* Ar = F1 + arow * S132;
                const unsigned int* B2 = gw + FF2B + lay * 16384 + (bcol << 8) + hf * 128;
#pragma unroll
                for (int ch = 0; ch < 4; ++ch) {
                    const AP2 ac = loadA32(Ar + kg + 32 * ch);
                    f2 = chunkG(ac, B2 + kg + 32 * ch, f2);
                }
            }
            __syncthreads();   // before next half overwrites F1
        }
        // FF2 epilogue: + b2 + h -> Abf (pre-LN2)
        {
            const int r0 = (wr << 4) + ((l >> 4) << 2);
            const float bb = fb2[lay * DM + bcol];
#pragma unroll
            for (int r = 0; r < 4; ++r) {
                const int row = r0 + r;
                Abf[row * S68 + bcol] = f2[r] + bb + unpackf(Hb[row * S68 + bcol]);
            }
        }
        __syncthreads();

        layernorm(Abf, Hb, l2g + lay * DM, l2b + lay * DM, n, jg);
        __syncthreads();
    }

    // ---- mean pool + classifier ----
    if (tid < DM) {
        float s = 0.f;
        for (int nn = 0; nn < NPG; ++nn) s += unpackf(Hb[nn * S68 + tid]);
        Abf[tid] = s * 0.015625f;
    }
    __syncthreads();
    if (tid < DM) {
        float acc = cb1[tid];
        for (int i = 0; i < DM; ++i) acc = fmaf(Abf[i], cW1[i * DM + tid], acc);
        Bbf[tid] = fmaxf(acc, 0.f);
    }
    __syncthreads();
    if (tid < NCLS) {
        float acc = cb2[tid];
        for (int i = 0; i < DM; ++i) acc = fmaf(Bbf[i], cW2[i * NCLS + tid], acc);
        out[g * NCLS + tid] = acc;
    }
}

extern "C" void kernel_launch(void* const* d_in, const int* in_sizes, int n_in,
                              void* d_out, int out_size, void* d_ws, size_t ws_size,
                              hipStream_t stream) {
    // dict order: x0 e1 c2 b3 emb4 Wgs5 Wgn6 Wq7 Wk8 Wv9 Wo10 bo11 l1g12 l1b13
    //             fW1_14 fb1_15 fW2_16 fb2_17 l2g18 l2b19 cW1_20 cb1_21 cW2_22 cb2_23
    unsigned int* wbuf =
        (d_ws != nullptr && ws_size >= (size_t)WTOT * 4) ? (unsigned int*)d_ws : nullptr;
    gt_prep<<<dim3(448), dim3(256), 0, stream>>>(
        (const float*)d_in[6], (const float*)d_in[5],   // Wgn, Wgs
        (const float*)d_in[8], (const float*)d_in[7],   // Wk, Wq
        (const float*)d_in[9], (const float*)d_in[10],  // Wv, Wo
        (const float*)d_in[14], (const float*)d_in[16],
        wbuf);
    gt_main<<<dim3(NG), dim3(1024), 0, stream>>>(
        (const int*)d_in[0], (const int*)d_in[1],
        (const float*)d_in[4], (const float*)d_in[11],
        (const float*)d_in[12], (const float*)d_in[13],
        (const float*)d_in[15], (const float*)d_in[17],
        (const float*)d_in[18], (const float*)d_in[19],
        (const float*)d_in[20], (const float*)d_in[21],
        (const float*)d_in[22], (const float*)d_in[23],
        wbuf,
        (float*)d_out);
}

// Round 12
// 80.456 us; speedup vs baseline: 1.1964x; 1.0259x over previous
//
#include <hip/hip_runtime.h>

#define NG 256
#define NPG 64
#define DM 64
#define DFF 256
#define NL 2
#define DEG 8
#define NCLS 10
#define S68 68
#define S132 132

// LDS pool offsets (u32 words)
#define HB0 0              // [64][68] packed-split h
#define AB0 4352           // [64][68] T (fp32) -> struct/attn (packed)
#define BB0 8704           // [64][68] agg/k/o (fp32)
#define QB0 13056          // [64][68] U/q (fp32)
#define F10 17408          // [64][68] v (fp32) then [64][132] packed f1 half
#define WSB 25856          // 3 x 4096-word staged weight pair buffers (48 KB)
#define POOLW 38144        // 152.6 KB

// prepped weight buffer: u16 elements, separate hi/lo bf16 planes
// W64 m=0..11 at u16 m*8192: hi plane [c][k 16B-unit-swizzled], lo at +4096
//   elem: c*64 + (((k>>3)^(c&7))<<3) + (k&7)
#define FF1B16 98304       // + lay*32768 + (c<<6) + k  (c<256,k<64), lo +16384
#define FF2B16 163840      // + lay*32768 + (c<<8) + k  (c<64,k<256), lo +16384
#define WTOT16 229376      // u16 count; 458 KB

__device__ __align__(16) unsigned short g_w[WTOT16];   // fallback if d_ws too small

typedef __attribute__((ext_vector_type(4))) float f32x4;
typedef __attribute__((ext_vector_type(4))) unsigned int u32x4;
typedef __attribute__((ext_vector_type(8))) __bf16 bf16x8;

// ---- split-bf16 packing: u32 = (lo16 << 16) | hi16,  x ~= hi + lo ----
__device__ __forceinline__ unsigned int packsplit(float x) {
    union { float f; unsigned int u; } a; a.f = x;
    const unsigned int t = a.u;
    const unsigned int hi = (t + 0x7FFFu + ((t >> 16) & 1u)) >> 16;   // RNE bf16(x)
    union { unsigned int u; float f; } hf; hf.u = hi << 16;
    union { float f; unsigned int u; } b; b.f = x - hf.f;
    const unsigned int tl = b.u;
    const unsigned int lo = (tl + 0x7FFFu + ((tl >> 16) & 1u)) & 0xFFFF0000u;
    return hi | lo;
}
__device__ __forceinline__ float unpackf(unsigned int u) {
    union { unsigned int u; float f; } h, l;
    h.u = u << 16;
    l.u = u & 0xFFFF0000u;
    return h.f + l.f;
}

// extract hi/lo bf16x8 frags from 8 packed u32 (A-side only)
__device__ __forceinline__ void extract(u32x4 p0, u32x4 p1, u32x4& hi, u32x4& lo) {
    hi[0] = (p0[0] & 0xFFFFu) | (p0[1] << 16);
    hi[1] = (p0[2] & 0xFFFFu) | (p0[3] << 16);
    hi[2] = (p1[0] & 0xFFFFu) | (p1[1] << 16);
    hi[3] = (p1[2] & 0xFFFFu) | (p1[3] << 16);
    lo[0] = (p0[0] >> 16) | (p0[1] & 0xFFFF0000u);
    lo[1] = (p0[2] >> 16) | (p0[3] & 0xFFFF0000u);
    lo[2] = (p1[0] >> 16) | (p1[1] & 0xFFFF0000u);
    lo[3] = (p1[2] >> 16) | (p1[3] & 0xFFFF0000u);
}

__device__ __forceinline__ bf16x8 ld8(const unsigned short* p) { return *(const bf16x8*)p; }

__device__ __forceinline__ f32x4 mfma16(u32x4 a, bf16x8 b, f32x4 c) {
    return __builtin_amdgcn_mfma_f32_16x16x32_bf16(__builtin_bit_cast(bf16x8, a), b, c, 0, 0, 0);
}

// pre-extracted A chunk (K=32)
struct AP2 { u32x4 h, l; };
__device__ __forceinline__ AP2 loadA32(const unsigned int* p) {
    const u32x4 a0 = *(const u32x4*)p, a1 = *(const u32x4*)(p + 4);
    AP2 r; extract(a0, a1, r.h, r.l); return r;
}

// acc += A_chunk * B_chunk, B given directly as hi/lo frags (3 MFMAs: hh, hl, lh)
__device__ __forceinline__ f32x4 chunkB(const AP2& a, bf16x8 bh, bf16x8 bl, f32x4 acc) {
    acc = mfma16(a.h, bh, acc);
    acc = mfma16(a.h, bl, acc);
    acc = mfma16(a.l, bh, acc);
    return acc;
}
// B from hi/lo planes at bp (+plane for lo)
__device__ __forceinline__ f32x4 chunkPl(const AP2& a, const unsigned short* bp, int plane,
                                         f32x4 acc) {
    return chunkB(a, ld8(bp), ld8(bp + plane), acc);
}

// full K=64 tile, B from swizzled staged LDS plane pair
__device__ __forceinline__ f32x4 mmS(const AP2& a0, const AP2& a1,
                                     const unsigned int* Wb, int bcol, int kg) {
    const unsigned short* P = (const unsigned short*)Wb;
    const int row = bcol << 6, cx = bcol & 7, u0 = kg >> 3;    // u0 in {0..3}
    const unsigned short* p0 = P + row + (((u0    ) ^ cx) << 3);
    const unsigned short* p1 = P + row + (((u0 + 4) ^ cx) << 3);
    f32x4 acc = {0.f, 0.f, 0.f, 0.f};
    acc = chunkB(a0, ld8(p0), ld8(p0 + 4096), acc);
    acc = chunkB(a1, ld8(p1), ld8(p1 + 4096), acc);
    return acc;
}

__device__ __forceinline__ void dwrite_f32(float* dst, f32x4 acc, int wr, int wc, int l) {
    const int col = (wc << 4) + (l & 15);
    const int r0 = (wr << 4) + ((l >> 4) << 2);
#pragma unroll
    for (int r = 0; r < 4; ++r) dst[(r0 + r) * S68 + col] = acc[r];
}

__device__ __forceinline__ void layernorm(const float* src, unsigned int* dst,
                                          const float* gp, const float* bp, int n, int jg) {
    const f32x4 v = *(const f32x4*)(src + n * S68 + jg);
    float s1 = v[0] + v[1] + v[2] + v[3];
    float s2 = v[0]*v[0] + v[1]*v[1] + v[2]*v[2] + v[3]*v[3];
    s1 += __shfl_xor(s1, 1); s1 += __shfl_xor(s1, 2);
    s1 += __shfl_xor(s1, 4); s1 += __shfl_xor(s1, 8);
    s2 += __shfl_xor(s2, 1); s2 += __shfl_xor(s2, 2);
    s2 += __shfl_xor(s2, 4); s2 += __shfl_xor(s2, 8);
    const float mean = s1 * 0.015625f;
    const float var  = s2 * 0.015625f - mean * mean;
    const float rstd = rsqrtf(var + 1e-5f);
    const f32x4 gm = *(const f32x4*)(gp + jg);
    const f32x4 bt = *(const f32x4*)(bp + jg);
    u32x4 p;
#pragma unroll
    for (int j = 0; j < 4; ++j) p[j] = packsplit((v[j] - mean) * rstd * gm[j] + bt[j]);
    *(u32x4*)(dst + n * S68 + jg) = p;
}

// ---- weight prep: fp32 -> transposed hi/lo bf16 planes (W64 16B-unit swizzled) ----
extern "C" __global__ void gt_prep(const float* __restrict__ Wgn, const float* __restrict__ Wgs,
                                   const float* __restrict__ Wk, const float* __restrict__ Wq,
                                   const float* __restrict__ Wv, const float* __restrict__ Wo,
                                   const float* __restrict__ fW1, const float* __restrict__ fW2,
                                   unsigned short* wout)
{
    unsigned short* W = wout ? wout : g_w;
    const int t = blockIdx.x * 256 + threadIdx.x;   // 0..114687
    float v; int dhi, plane;
    if (t < 49152) {
        const int m = t >> 12, r = t & 4095, k = r >> 6, c = r & 63;
        const int lay = m / 6, idx = m - lay * 6;
        const float* s;
        switch (idx) { case 0: s = Wgn; break; case 1: s = Wgs; break;
                       case 2: s = Wk;  break; case 3: s = Wq;  break;
                       case 4: s = Wv;  break; default: s = Wo; }
        v = s[lay * 4096 + k * 64 + c];
        dhi = (m << 13) + (c << 6) + ((((k >> 3) ^ (c & 7)) << 3) | (k & 7));  // swizzled
        plane = 4096;
    } else if (t < 81920) {
        const int r = t - 49152, lay = r >> 14, q = r & 16383, k = q >> 8, c = q & 255;
        v = fW1[lay * 16384 + k * 256 + c];
        dhi = FF1B16 + lay * 32768 + (c << 6) + k;
        plane = 16384;
    } else {
        const int r = t - 81920, lay = r >> 14, q = r & 16383, k = q >> 6, c = q & 63;
        v = fW2[lay * 16384 + k * 64 + c];
        dhi = FF2B16 + lay * 32768 + (c << 8) + k;
        plane = 16384;
    }
    union { float f; unsigned int u; } a; a.f = v;
    const unsigned int hi = (a.u + 0x7FFFu + ((a.u >> 16) & 1u)) >> 16;
    union { unsigned int u; float f; } hf; hf.u = hi << 16;
    union { float f; unsigned int u; } b; b.f = v - hf.f;
    const unsigned int lo = (b.u + 0x7FFFu + ((b.u >> 16) & 1u)) >> 16;
    W[dhi] = (unsigned short)hi;
    W[dhi + plane] = (unsigned short)lo;
}

extern "C" __global__ __launch_bounds__(1024)
void gt_main(const int* __restrict__ x, const int* __restrict__ e_src,
             const float* __restrict__ emb, const float* __restrict__ bo,
             const float* __restrict__ l1g, const float* __restrict__ l1b,
             const float* __restrict__ fb1, const float* __restrict__ fb2,
             const float* __restrict__ l2g, const float* __restrict__ l2b,
             const float* __restrict__ cW1, const float* __restrict__ cb1,
             const float* __restrict__ cW2, const float* __restrict__ cb2,
             const unsigned short* __restrict__ wext,
             float* __restrict__ out)
{
    const unsigned short* gw16 = wext ? wext : g_w;
    const unsigned int*   gwu  = (const unsigned int*)gw16;

    __shared__ __align__(16) unsigned int pool[POOLW];
    unsigned int* Hb  = pool + HB0;
    unsigned int* Abu = pool + AB0;  float* Abf = (float*)Abu;
    float* Bbf = (float*)(pool + BB0);
    float* Qbf = (float*)(pool + QB0);
    float* Vbf = (float*)(pool + F10);
    unsigned int* F1  = pool + F10;
    unsigned int* Wb0 = pool + WSB;
    unsigned int* Wb1 = pool + WSB + 4096;
    unsigned int* Wb2 = pool + WSB + 8192;

    const int g = blockIdx.x, tid = threadIdx.x;
    const int w = tid >> 6, l = tid & 63;
    const int wr = w >> 2, wc = w & 3;
    const int n = tid >> 4, jg = (tid & 15) << 2;

    const int arow = (wr << 4) + (l & 15);
    const int bcol = (wc << 4) + (l & 15);
    const int kg   = (l >> 4) << 3;
    const int t4   = tid << 2;

    // ---- h = emb[x] (packed) ; prologue staging of Wgn0/Wgs0/Wv0 pairs ----
    {
        const u32x4 s0 = *(const u32x4*)(gwu + (0 << 12) + t4);
        const u32x4 s1 = *(const u32x4*)(gwu + (1 << 12) + t4);
        const u32x4 s2 = *(const u32x4*)(gwu + (4 << 12) + t4);
        const int lbl = x[g * NPG + n];
        const f32x4 e = *(const f32x4*)(emb + lbl * DM + jg);
        u32x4 p;
#pragma unroll
        for (int j = 0; j < 4; ++j) p[j] = packsplit(e[j]);
        *(u32x4*)(Hb + n * S68 + jg) = p;
        *(u32x4*)(Wb0 + t4) = s0;
        *(u32x4*)(Wb1 + t4) = s1;
        *(u32x4*)(Wb2 + t4) = s2;
    }
    __syncthreads();

    for (int lay = 0; lay < NL; ++lay) {
        const bool pre = (lay + 1 < NL);

        // p1: T = h@Wgn -> Abf ; U = h@Wgs -> Qbf ; v = h@Wv -> Vbf (B staged)
        {
            const unsigned int* Ar = Hb + arow * S68;
            const AP2 a0 = loadA32(Ar + kg), a1 = loadA32(Ar + kg + 32);
            dwrite_f32(Abf, mmS(a0, a1, Wb0, bcol, kg), wr, wc, l);
            dwrite_f32(Qbf, mmS(a0, a1, Wb1, bcol, kg), wr, wc, l);
            dwrite_f32(Vbf, mmS(a0, a1, Wb2, bcol, kg), wr, wc, l);
        }
        __syncthreads();

        // p2: agg over 8 incoming edges of T -> Bbf ; stage Wk->b0, Wq->b1
        {
            const u32x4 t0 = *(const u32x4*)(gwu + ((lay * 6 + 2) << 12) + t4);
            const u32x4 t1 = *(const u32x4*)(gwu + ((lay * 6 + 3) << 12) + t4);
            f32x4 s = {0.f, 0.f, 0.f, 0.f};
            const int* es = e_src + (g * NPG + n) * DEG;
#pragma unroll
            for (int k = 0; k < DEG; ++k) {
                const int sr = es[k] - g * NPG;
                const f32x4 v4 = *(const f32x4*)(Abf + sr * S68 + jg);
                s[0] += v4[0]; s[1] += v4[1]; s[2] += v4[2]; s[3] += v4[3];
            }
            *(f32x4*)(Bbf + n * S68 + jg) = s;
            *(u32x4*)(Wb0 + t4) = t0;
            *(u32x4*)(Wb1 + t4) = t1;
        }
        __syncthreads();

        // p3: struct = h + relu(U + agg) -> Abu (packed) ; stage Wo->b2
        {
            const u32x4 t2 = *(const u32x4*)(gwu + ((lay * 6 + 5) << 12) + t4);
            const f32x4 u4 = *(const f32x4*)(Qbf + n * S68 + jg);
            const f32x4 a4 = *(const f32x4*)(Bbf + n * S68 + jg);
            const u32x4 hp = *(const u32x4*)(Hb + n * S68 + jg);
            u32x4 p;
#pragma unroll
            for (int j = 0; j < 4; ++j)
                p[j] = packsplit(unpackf(hp[j]) + fmaxf(u4[j] + a4[j], 0.f));
            *(u32x4*)(Abu + n * S68 + jg) = p;
            *(u32x4*)(Wb2 + t4) = t2;
        }
        __syncthreads();

        // p4: k = St@Wk -> Bbf ; q = St@Wq -> Qbf (staged B)
        {
            const unsigned int* Ar = Abu + arow * S68;
            const AP2 a0 = loadA32(Ar + kg), a1 = loadA32(Ar + kg + 32);
            dwrite_f32(Bbf, mmS(a0, a1, Wb0, bcol, kg), wr, wc, l);
            dwrite_f32(Qbf, mmS(a0, a1, Wb1, bcol, kg), wr, wc, l);
        }
        __syncthreads();

        // p5: attention with ONLINE-MAX softmax (required: edge resampling makes
        //     heavy-tailed scores; no-max overflows exp -> row zeroed, rounds 6/7/11)
        //     -> Abu ; stage next-layer Wgn->b0, Wgs->b1
        {
            u32x4 t0, t1;
            if (pre) {
                t0 = *(const u32x4*)(gwu + (((lay + 1) * 6 + 0) << 12) + t4);
                t1 = *(const u32x4*)(gwu + (((lay + 1) * 6 + 1) << 12) + t4);
            }
            const f32x4 qr = *(const f32x4*)(Qbf + n * S68 + jg);
            const float q0 = qr[0] * 0.25f, q1 = qr[1] * 0.25f;
            const float q2 = qr[2] * 0.25f, q3 = qr[3] * 0.25f;
            float o0 = 0.f, o1 = 0.f, o2 = 0.f, o3 = 0.f, m = -1e30f, ls = 0.f;
#pragma unroll 4
            for (int sr = 0; sr < NPG; ++sr) {
                const f32x4 k4 = *(const f32x4*)(Bbf + sr * S68 + jg);
                float s = q0*k4[0] + q1*k4[1] + q2*k4[2] + q3*k4[3];
                s += __shfl_xor(s, 1);
                s += __shfl_xor(s, 2);        // full 16-dim head dot (4 lanes)
                const float mn  = fmaxf(m, s);
                const float fac = __expf(m - mn), wg = __expf(s - mn);
                ls = ls * fac + wg;
                const f32x4 v4 = *(const f32x4*)(Vbf + sr * S68 + jg);
                o0 = o0 * fac + wg * v4[0]; o1 = o1 * fac + wg * v4[1];
                o2 = o2 * fac + wg * v4[2]; o3 = o3 * fac + wg * v4[3];
                m = mn;
            }
            const float il = 1.f / ls;
            u32x4 p;
            p[0] = packsplit(o0 * il); p[1] = packsplit(o1 * il);
            p[2] = packsplit(o2 * il); p[3] = packsplit(o3 * il);
            *(u32x4*)(Abu + n * S68 + jg) = p;
            if (pre) {
                *(u32x4*)(Wb0 + t4) = t0;
                *(u32x4*)(Wb1 + t4) = t1;
            }
        }
        __syncthreads();

        // p6: o = attn@Wo + bo + h -> Bbf (pre-LN1), staged B in b2
        {
            const unsigned int* Ar = Abu + arow * S68;
            const AP2 a0 = loadA32(Ar + kg), a1 = loadA32(Ar + kg + 32);
            const f32x4 acc = mmS(a0, a1, Wb2, bcol, kg);
            const int r0 = (wr << 4) + ((l >> 4) << 2);
            const float bb = bo[lay * DM + bcol];
#pragma unroll
            for (int r = 0; r < 4; ++r) {
                const int row = r0 + r;
                Bbf[row * S68 + bcol] = acc[r] + bb + unpackf(Hb[row * S68 + bcol]);
            }
        }
        __syncthreads();

        // LN1 ; stage next-layer Wv->b2
        {
            u32x4 t2;
            if (pre) t2 = *(const u32x4*)(gwu + (((lay + 1) * 6 + 4) << 12) + t4);
            layernorm(Bbf, Hb, l1g + lay * DM, l1b + lay * DM, n, jg);
            if (pre) *(u32x4*)(Wb2 + t4) = t2;
        }
        __syncthreads();

        // ---- FF in 2 halves of 128 hidden (B from global hi/lo planes) ----
        f32x4 f2 = {0.f, 0.f, 0.f, 0.f};
        for (int hf = 0; hf < 2; ++hf) {
            // FF1: 2 col-tiles per wave -> F1 packed [64][132]
            {
                const unsigned int* Ar = Hb + arow * S68;
                const AP2 a0 = loadA32(Ar + kg), a1 = loadA32(Ar + kg + 32);
                const unsigned short* B1 = gw16 + FF1B16 + lay * 32768;
                const int r0 = (wr << 4) + ((l >> 4) << 2);
#pragma unroll
                for (int t = 0; t < 2; ++t) {
                    const int tc = ((wc + 4 * t) << 4) + (l & 15);   // col within half
                    const int cg = hf * 128 + tc;
                    const unsigned short* Bp = B1 + (cg << 6);
                    f32x4 acc = {0.f, 0.f, 0.f, 0.f};
                    acc = chunkPl(a0, Bp + kg,      16384, acc);
                    acc = chunkPl(a1, Bp + kg + 32, 16384, acc);
                    const float b1 = fb1[lay * DFF + cg];
#pragma unroll
                    for (int r = 0; r < 4; ++r)
                        F1[(r0 + r) * S132 + tc] = packsplit(fmaxf(acc[r] + b1, 0.f));
                }
            }
            __syncthreads();
            // FF2: K=128 of this half, accumulate into f2
            {
                const unsigned int* Ar = F1 + arow * S132;
                const unsigned short* B2 = gw16 + FF2B16 + lay * 32768 + (bcol << 8) + hf * 128;
#pragma unroll
                for (int ch = 0; ch < 4; ++ch) {
                    const AP2 ac = loadA32(Ar + kg + 32 * ch);
                    f2 = chunkPl(ac, B2 + kg + 32 * ch, 16384, f2);
                }
            }
            __syncthreads();   // before next half overwrites F1
        }
        // FF2 epilogue: + b2 + h -> Abf (pre-LN2)
        {
            const int r0 = (wr << 4) + ((l >> 4) << 2);
            const float bb = fb2[lay * DM + bcol];
#pragma unroll
            for (int r = 0; r < 4; ++r) {
                const int row = r0 + r;
                Abf[row * S68 + bcol] = f2[r] + bb + unpackf(Hb[row * S68 + bcol]);
            }
        }
        __syncthreads();

        layernorm(Abf, Hb, l2g + lay * DM, l2b + lay * DM, n, jg);
        __syncthreads();
    }

    // ---- mean pool + classifier ----
    if (tid < DM) {
        float s = 0.f;
        for (int nn = 0; nn < NPG; ++nn) s += unpackf(Hb[nn * S68 + tid]);
        Abf[tid] = s * 0.015625f;
    }
    __syncthreads();
    if (tid < DM) {
        float acc = cb1[tid];
        for (int i = 0; i < DM; ++i) acc = fmaf(Abf[i], cW1[i * DM + tid], acc);
        Bbf[tid] = fmaxf(acc, 0.f);
    }
    __syncthreads();
    if (tid < NCLS) {
        float acc = cb2[tid];
        for (int i = 0; i < DM; ++i) acc = fmaf(Bbf[i], cW2[i * NCLS + tid], acc);
        out[g * NCLS + tid] = acc;
    }
}

extern "C" void kernel_launch(void* const* d_in, const int* in_sizes, int n_in,
                              void* d_out, int out_size, void* d_ws, size_t ws_size,
                              hipStream_t stream) {
    // dict order: x0 e1 c2 b3 emb4 Wgs5 Wgn6 Wq7 Wk8 Wv9 Wo10 bo11 l1g12 l1b13
    //             fW1_14 fb1_15 fW2_16 fb2_17 l2g18 l2b19 cW1_20 cb1_21 cW2_22 cb2_23
    unsigned short* wbuf =
        (d_ws != nullptr && ws_size >= (size_t)WTOT16 * 2) ? (unsigned short*)d_ws : nullptr;
    gt_prep<<<dim3(448), dim3(256), 0, stream>>>(
        (const float*)d_in[6], (const float*)d_in[5],   // Wgn, Wgs
        (const float*)d_in[8], (const float*)d_in[7],   // Wk, Wq
        (const float*)d_in[9], (const float*)d_in[10],  // Wv, Wo
        (const float*)d_in[14], (const float*)d_in[16],
        wbuf);
    gt_main<<<dim3(NG), dim3(1024), 0, stream>>>(
        (const int*)d_in[0], (const int*)d_in[1],
        (const float*)d_in[4], (const float*)d_in[11],
        (const float*)d_in[12], (const float*)d_in[13],
        (const float*)d_in[15], (const float*)d_in[17],
        (const float*)d_in[18], (const float*)d_in[19],
        (const float*)d_in[20], (const float*)d_in[21],
        (const float*)d_in[22], (const float*)d_in[23],
        wbuf,
        (float*)d_out);
}